// Round 10
// baseline (525.032 us; speedup 1.0000x reference)
//
#include <hip/hip_runtime.h>

#define TOKENS 8192
#define D_IN   4096
#define D_OUT  4096

typedef _Float16 f16;
typedef __attribute__((ext_vector_type(8))) _Float16 half8;
typedef __attribute__((ext_vector_type(4))) float    f32x4;
typedef __attribute__((address_space(3))) char       lds_char;

// ---------------- conversion kernels ----------------

__global__ void cvt_x_kernel(const float* __restrict__ x, f16* __restrict__ xh) {
    size_t i = ((size_t)blockIdx.x * blockDim.x + threadIdx.x) * 4;
    float4 v = *reinterpret_cast<const float4*>(x + i);
    union { f16 h[4]; uint2 u; } p;
    p.h[0] = (f16)v.x; p.h[1] = (f16)v.y; p.h[2] = (f16)v.z; p.h[3] = (f16)v.w;
    *reinterpret_cast<uint2*>(xh + i) = p.u;
}

__global__ void cvt_w_kernel(const int* __restrict__ w, f16* __restrict__ wh,
                             const float* __restrict__ scale_p,
                             const int* __restrict__ zp_p) {
    size_t i = ((size_t)blockIdx.x * blockDim.x + threadIdx.x) * 4;
    float s = scale_p[0];
    float z = (float)zp_p[0];
    int4 v = *reinterpret_cast<const int4*>(w + i);
    union { f16 h[4]; uint2 u; } p;
    p.h[0] = (f16)(((float)v.x - z) * s);
    p.h[1] = (f16)(((float)v.y - z) * s);
    p.h[2] = (f16)(((float)v.z - z) * s);
    p.h[3] = (f16)(((float)v.w - z) * s);
    *reinterpret_cast<uint2*>(wh + i) = p.u;
}

// ---------------- GEMM: 256x256, BK=64, 8 waves, DEEP-LEAD 4-phase --------
// R10. R3-R8 all 46% MfmaUtil: every variant drained stage groups with only
// 1-2 phase lead (~640-1300cy) vs ~900-1200cy DMA latency, and reads shared
// a barrier epoch with their consuming MFMA -> MFMA/LDS/DMA streams SUMMED.
// This schedule gives every stage->read edge a constant 4-phase (~2500cy)
// lead and every read a >=1-phase MFMA shadow.
//
// Span (4 phases) per tile t; buffer parity t&1; stages go to tile t+1:
//  ph1: VMCNT(6);BAR; [wc<2:  rd b0n,b1n(t)]; Q01(t-1); stage B0,B1(t+1)
//  ph2: VMCNT(6);BAR; [wc>=2: rd b0n,b1n(t)]; Q11(t-1); b1c=b1n; stage B2,B3
//  ph3: VMCNT(6);BAR; Q10(t-1); [wr0: rd a0,a1(t)];     b0c=b0n; stage A0,A1
//  ph4: VMCNT(6);BAR; [wr1: rd a0,a1(t)]; Q00(t);                stage A2,A3
// Stage order B01|B23|A01|A23 matches read phases with exact 4-phase lag.
//
// vmcnt ledger (2 calls/phase): at each phase start outstanding=8; VMCNT(6)
// retires exactly the pair staged 4 phases ago (the pair this phase reads).
// Final span (no stages): 6/4/2/0 (R2 lesson: counted drains no-op when the
// queue is short). Span 0: drains no-op (prologue did VMCNT(0)+BAR).
//
// WAR edges (stage overwrites buf of tile t-1 during span t): every read of
// t-1 is lgkm-retired BEFORE the overwriting stage by an architectural
// dependence on the SAME wave: b-reads retire at the b1c/b0c register
// copies (ph2/ph3 of their own span); a0 retires at Q00(ph4); a1 at
// Q11/Q10 (ph2/ph3 of next span) -- each precedes the overwriting stage's
// phase barrier, and cross-wave order follows from that barrier.
// Reads and in-phase stages target DIFFERENT buffer halves -> no alias.
//
// Register plan: acc 128 + a0 16 + a1 16 + b0c/b0n 16 + b1c/b1n 16 ≈ 200
// -> 8 waves/CU (unchanged). Copies = 16 v_mov x2 per tile (~1%).

#define BM 256
#define BN 256
#define BK 64
#define NT (D_IN / BK)      // 64 K-tiles
#define LDS_BUF   65536
#define LDS_B_OFF 32768

__device__ __forceinline__ void stage16(const f16* g, lds_char* l) {
    __builtin_amdgcn_global_load_lds(
        (const __attribute__((address_space(1))) void*)g,
        (__attribute__((address_space(3))) void*)l, 16, 0, 0);
}

#define LDS_LOAD8(p) (*(const __attribute__((address_space(3))) half8*)(p))

#define LOAD_AQ(DST, BUF, QM)                                               \
    do { _Pragma("unroll")                                                  \
        for (int fm = 0; fm < 4; ++fm) {                                    \
            int rr = wr * 128 + (QM) * 64 + fm * 16 + lr;                   \
            _Pragma("unroll")                                               \
            for (int ks = 0; ks < 2; ++ks)                                  \
                DST[fm][ks] = LDS_LOAD8((BUF) + rr * 128 +                  \
                                        ((cb0 + ks * 64) ^ swzr));          \
        } } while (0)

#define LOAD_BQ(DST, BUF, QN)                                               \
    do { _Pragma("unroll")                                                  \
        for (int fn = 0; fn < 2; ++fn) {                                    \
            int rr = wc * 64 + (QN) * 32 + fn * 16 + lr;                    \
            _Pragma("unroll")                                               \
            for (int ks = 0; ks < 2; ++ks)                                  \
                DST[fn][ks] = LDS_LOAD8((BUF) + rr * 128 +                  \
                                        ((cb0 + ks * 64) ^ swzr));          \
        } } while (0)

#define MFMA_Q(QM, QN, AV, BV)                                              \
    do { _Pragma("unroll")                                                  \
        for (int fm = 0; fm < 4; ++fm) {                                    \
            _Pragma("unroll")                                               \
            for (int fn = 0; fn < 2; ++fn) {                                \
                _Pragma("unroll")                                           \
                for (int ks = 0; ks < 2; ++ks)                              \
                    acc[(QM)*4+fm][(QN)*2+fn] =                             \
                        __builtin_amdgcn_mfma_f32_16x16x32_f16(             \
                            AV[fm][ks], BV[fn][ks],                         \
                            acc[(QM)*4+fm][(QN)*2+fn], 0, 0, 0);            \
            }                                                               \
        } } while (0)

#define COPYB(DST, SRC)                                                     \
    do { _Pragma("unroll")                                                  \
        for (int fn = 0; fn < 2; ++fn)                                      \
            _Pragma("unroll")                                               \
            for (int ks = 0; ks < 2; ++ks) DST[fn][ks] = SRC[fn][ks];       \
    } while (0)

#define BAR()      __builtin_amdgcn_s_barrier()
#define VMCNT(N)   asm volatile("s_waitcnt vmcnt(" #N ")" ::: "memory")
#define PRIO(x)    __builtin_amdgcn_s_setprio(x)

__global__ __launch_bounds__(512, 2)
void gemm_dl(const f16* __restrict__ A, const f16* __restrict__ B,
             const float* __restrict__ bias,
             const float* __restrict__ oscale_p, const int* __restrict__ ozp_p,
             float* __restrict__ C)
{
    __shared__ __align__(1024) char smem_[2 * LDS_BUF];   // 128 KiB
    lds_char* smem = (lds_char*)smem_;
    constexpr int K = D_IN, N = D_OUT;

    // XCD-aware bijective swizzle (grid = 512, divisible by 8)
    int nwg = gridDim.x;
    int cpx = nwg >> 3;
    int bid = blockIdx.x;
    int swz = (bid & 7) * cpx + (bid >> 3);
    int ntn = N / BN;                        // 16
    int m0 = (swz / ntn) * BM;
    int n0 = (swz % ntn) * BN;

    int tid = threadIdx.x;
    int l   = tid & 63;
    int wv  = tid >> 6;                      // 0..7
    int wr  = wv >> 2;                       // 0..1 (M)
    int wc  = wv & 3;                        // 0..3 (N)

    // staging: lane l -> row = wv*8 + (l>>3), phys slot = l&7;
    // pre-swizzled global col = ((l&7) ^ (l>>3)) * 8 f16.
    int srow = wv * 8 + (l >> 3);
    int scol = ((l & 7) ^ (l >> 3)) * 8;
    const f16* gA = A + (size_t)(m0 + srow) * K + scol;
    const f16* gB = B + (size_t)(n0 + srow) * K + scol;
    lds_char* dstbase = smem + wv * 1024 + l * 16;

    // read-side per-lane constants
    int lr   = l & 15;
    int swzr = (l & 7) << 4;
    int cb0  = (l >> 4) * 16;

    f32x4 acc[8][4] = {};
    half8 a0[4][2], a1[4][2];
    half8 b0c[2][2], b0n[2][2], b1c[2][2], b1n[2][2];

    // ---- prologue: stage tile 0 (order B0..B3, A0..A3), drain, barrier
    #pragma unroll
    for (int q = 0; q < 4; ++q)
        stage16(gB + (size_t)q * 64 * K, dstbase + LDS_B_OFF + q * 8192);
    #pragma unroll
    for (int q = 0; q < 4; ++q)
        stage16(gA + (size_t)q * 64 * K, dstbase + q * 8192);
    VMCNT(0);
    BAR();

    // ================= span 0 (t = 0): no prev-tile MFMAs =================
    {
        const lds_char* bufA = smem;
        const lds_char* bufB = smem + LDS_B_OFF;
        lds_char* dst = dstbase + LDS_BUF;       // tile 1 -> buf1
        const f16* nA = gA + BK;
        const f16* nB = gB + BK;

        // ph1
        if (wc < 2) { LOAD_BQ(b0n, bufB, 0); LOAD_BQ(b1n, bufB, 1); }
        stage16(nB,                   dst + LDS_B_OFF);
        stage16(nB + (size_t)64 * K,  dst + LDS_B_OFF + 8192);
        // ph2
        BAR();
        if (wc >= 2) { LOAD_BQ(b0n, bufB, 0); LOAD_BQ(b1n, bufB, 1); }
        COPYB(b1c, b1n);
        stage16(nB + (size_t)128 * K, dst + LDS_B_OFF + 2 * 8192);
        stage16(nB + (size_t)192 * K, dst + LDS_B_OFF + 3 * 8192);
        // ph3
        BAR();
        if (wr == 0) { LOAD_AQ(a0, bufA, 0); LOAD_AQ(a1, bufA, 1); }
        COPYB(b0c, b0n);
        stage16(nA,                   dst);
        stage16(nA + (size_t)64 * K,  dst + 8192);
        // ph4
        BAR();
        if (wr == 1) { LOAD_AQ(a0, bufA, 0); LOAD_AQ(a1, bufA, 1); }
        PRIO(1); MFMA_Q(0, 0, a0, b0c); PRIO(0);
        stage16(nA + (size_t)128 * K, dst + 2 * 8192);
        stage16(nA + (size_t)192 * K, dst + 3 * 8192);
    }

    // ================= main loop t = 1 .. NT-2 =================
    for (int t = 1; t < NT - 1; ++t) {
        const lds_char* bufA = smem + (t & 1) * LDS_BUF;
        const lds_char* bufB = bufA + LDS_B_OFF;
        lds_char* dst = dstbase + ((t + 1) & 1) * LDS_BUF;
        const f16* nA = gA + (size_t)(t + 1) * BK;
        const f16* nB = gB + (size_t)(t + 1) * BK;

        // ph1: Q01(t-1)
        VMCNT(6); BAR();
        if (wc < 2) { LOAD_BQ(b0n, bufB, 0); LOAD_BQ(b1n, bufB, 1); }
        PRIO(1); MFMA_Q(0, 1, a0, b1c); PRIO(0);
        stage16(nB,                   dst + LDS_B_OFF);
        stage16(nB + (size_t)64 * K,  dst + LDS_B_OFF + 8192);

        // ph2: Q11(t-1)
        VMCNT(6); BAR();
        if (wc >= 2) { LOAD_BQ(b0n, bufB, 0); LOAD_BQ(b1n, bufB, 1); }
        PRIO(1); MFMA_Q(1, 1, a1, b1c); PRIO(0);
        COPYB(b1c, b1n);
        stage16(nB + (size_t)128 * K, dst + LDS_B_OFF + 2 * 8192);
        stage16(nB + (size_t)192 * K, dst + LDS_B_OFF + 3 * 8192);

        // ph3: Q10(t-1) BEFORE reads (a1 reuse), then a-reads for wr0
        VMCNT(6); BAR();
        PRIO(1); MFMA_Q(1, 0, a1, b0c); PRIO(0);
        if (wr == 0) { LOAD_AQ(a0, bufA, 0); LOAD_AQ(a1, bufA, 1); }
        COPYB(b0c, b0n);
        stage16(nA,                   dst);
        stage16(nA + (size_t)64 * K,  dst + 8192);

        // ph4: Q00(t)
        VMCNT(6); BAR();
        if (wr == 1) { LOAD_AQ(a0, bufA, 0); LOAD_AQ(a1, bufA, 1); }
        PRIO(1); MFMA_Q(0, 0, a0, b0c); PRIO(0);
        stage16(nA + (size_t)128 * K, dst + 2 * 8192);
        stage16(nA + (size_t)192 * K, dst + 3 * 8192);
    }

    // ================= final span (t = NT-1): no stages, decaying drains ===
    {
        const lds_char* bufA = smem + ((NT - 1) & 1) * LDS_BUF;
        const lds_char* bufB = bufA + LDS_B_OFF;

        // ph1
        VMCNT(6); BAR();
        if (wc < 2) { LOAD_BQ(b0n, bufB, 0); LOAD_BQ(b1n, bufB, 1); }
        PRIO(1); MFMA_Q(0, 1, a0, b1c); PRIO(0);
        // ph2
        VMCNT(4); BAR();
        if (wc >= 2) { LOAD_BQ(b0n, bufB, 0); LOAD_BQ(b1n, bufB, 1); }
        PRIO(1); MFMA_Q(1, 1, a1, b1c); PRIO(0);
        COPYB(b1c, b1n);
        // ph3
        VMCNT(2); BAR();
        PRIO(1); MFMA_Q(1, 0, a1, b0c); PRIO(0);
        if (wr == 0) { LOAD_AQ(a0, bufA, 0); LOAD_AQ(a1, bufA, 1); }
        COPYB(b0c, b0n);
        // ph4
        VMCNT(0); BAR();
        if (wr == 1) { LOAD_AQ(a0, bufA, 0); LOAD_AQ(a1, bufA, 1); }
        PRIO(1);
        MFMA_Q(0, 0, a0, b0c);
        // drain-out: remaining quadrants of tile NT-1
        MFMA_Q(0, 1, a0, b1c);
        MFMA_Q(1, 1, a1, b1c);
        MFMA_Q(1, 0, a1, b0c);
        PRIO(0);
    }

    // ---- epilogue: bias + fake-quantize (round-half-even = jnp.round)
    float os  = oscale_p[0];
    float ozp = (float)ozp_p[0];
    float inv = 1.0f / os;
    #pragma unroll
    for (int qm = 0; qm < 2; ++qm) {
        #pragma unroll
        for (int fm = 0; fm < 4; ++fm) {
            int rowb = m0 + wr * 128 + qm * 64 + fm * 16 + (l >> 4) * 4;
            #pragma unroll
            for (int qn = 0; qn < 2; ++qn) {
                #pragma unroll
                for (int fn = 0; fn < 2; ++fn) {
                    int col = n0 + wc * 64 + qn * 32 + fn * 16 + lr;
                    float bv = bias[col];
                    f32x4 v = acc[qm * 4 + fm][qn * 2 + fn];
                    #pragma unroll
                    for (int j = 0; j < 4; ++j) {
                        float o = v[j] + bv;
                        float q = rintf(o * inv) + ozp;
                        q = fminf(fmaxf(q, 0.0f), 255.0f);
                        C[(size_t)(rowb + j) * N + col] = (q - ozp) * os;
                    }
                }
            }
        }
    }
}

// ---------------- launch ----------------

extern "C" void kernel_launch(void* const* d_in, const int* in_sizes, int n_in,
                              void* d_out, int out_size, void* d_ws, size_t ws_size,
                              hipStream_t stream) {
    const float* x      = (const float*)d_in[0];
    const int*   w8     = (const int*)d_in[1];
    const float* wscale = (const float*)d_in[2];
    const int*   wzp    = (const int*)d_in[3];
    const float* bias   = (const float*)d_in[4];
    const float* oscale = (const float*)d_in[5];
    const int*   ozp    = (const int*)d_in[6];
    float* out = (float*)d_out;

    const size_t x_elems = (size_t)TOKENS * D_IN;
    const size_t w_elems = (size_t)D_OUT * D_IN;
    const size_t need = (x_elems + w_elems) * sizeof(f16);
    if (ws_size < need) return;

    f16* xh = (f16*)d_ws;
    f16* wh = xh + x_elems;

    {
        int blocks = (int)(x_elems / 4 / 256);
        cvt_x_kernel<<<blocks, 256, 0, stream>>>(x, xh);
    }
    {
        int blocks = (int)(w_elems / 4 / 256);
        cvt_w_kernel<<<blocks, 256, 0, stream>>>(w8, wh, wscale, wzp);
    }
    {
        int grid = (TOKENS / BM) * (D_OUT / BN);   // 32 * 16 = 512, %8 == 0
        gemm_dl<<<grid, 512, 0, stream>>>(xh, wh, bias, oscale, ozp, out);
    }
}

// Round 11
// 403.757 us; speedup vs baseline: 1.3004x; 1.3004x over previous
//
#include <hip/hip_runtime.h>

#define TOKENS 8192
#define D_IN   4096
#define D_OUT  4096

typedef _Float16 f16;
typedef __attribute__((ext_vector_type(8))) _Float16 half8;
typedef __attribute__((ext_vector_type(4))) float    f32x4;
typedef __attribute__((address_space(3))) char       lds_char;

// ---------------- conversion kernels ----------------

__global__ void cvt_x_kernel(const float* __restrict__ x, f16* __restrict__ xh) {
    size_t i = ((size_t)blockIdx.x * blockDim.x + threadIdx.x) * 4;
    float4 v = *reinterpret_cast<const float4*>(x + i);
    union { f16 h[4]; uint2 u; } p;
    p.h[0] = (f16)v.x; p.h[1] = (f16)v.y; p.h[2] = (f16)v.z; p.h[3] = (f16)v.w;
    *reinterpret_cast<uint2*>(xh + i) = p.u;
}

__global__ void cvt_w_kernel(const int* __restrict__ w, f16* __restrict__ wh,
                             const float* __restrict__ scale_p,
                             const int* __restrict__ zp_p) {
    size_t i = ((size_t)blockIdx.x * blockDim.x + threadIdx.x) * 4;
    float s = scale_p[0];
    float z = (float)zp_p[0];
    int4 v = *reinterpret_cast<const int4*>(w + i);
    union { f16 h[4]; uint2 u; } p;
    p.h[0] = (f16)(((float)v.x - z) * s);
    p.h[1] = (f16)(((float)v.y - z) * s);
    p.h[2] = (f16)(((float)v.z - z) * s);
    p.h[3] = (f16)(((float)v.w - z) * s);
    *reinterpret_cast<uint2*>(wh + i) = p.u;
}

// ---------------- GEMM: 256x256, BK=64, 8 waves, B-direct-to-registers ----
// R11. R3-R10 post-mortem: all LDS-staged schedules pin 46% MfmaUtil because
// the LDS port (192KB reads + 64KB DMA writes per K-tile/CU ~ 2300cy) rivals
// the MFMA pipe (~2480cy) and they serialize at the lgkm waits. Fix = cut
// LDS traffic: B-fragments are 16B-contiguous in the K-major layout, so B
// loads GLOBAL->REG directly (prefetch 1 K-tile ahead, alternating register
// banks, compile-time names); LDS keeps only A (reuse x4 across n-waves):
// 2 x 32KB dbuf, staged 1 tile ahead. LDS port drops to ~1250cy << MFMA.
//
// vmcnt ledger (FIFO; per tile issue order: A(t+1) stage x4, FENCE,
// B(t+1) load x8 -> 12 ops/tile):
//   top of tile t: outstanding = A(t)x4 + B(t)x8 = 12
//   M1 = VMCNT(8): retires A(t) (oldest 4). BAR. ds_read A from buf[t&1].
//   issue A(t+1)x4 -> 12; FENCE (pins A-before-B issue order); B(t+1)x8 -> 20
//   M2 = VMCNT(12): retires B(t) -> bC resident for this tile's MFMA.
//   Tail (t=NT-1, stages nothing): M1 = VMCNT(8) (retires A(63)),
//   M2 = VMCNT(0) (retires B(63)) -- R2 lesson: counted drains no-op short.
// Protocol (R5 lesson): M1 drain -> BAR -> ds_read at the one consume point.
// WAR (stage A(t+1) overwrites buf read in t-1): t-1's reads lgkm-retired
// before their consuming MFMAs, all before BAR(t); stages issue after BAR(t).
//
// A-reads pipelined in 4 quarter-clusters: rd aQ(i+1) [4 x ds_read_b128]
// issues before CLUST(i) [16 MFMA], 2 register banks (aqa: q0,q2; aqb: q1,q3).
//
// XCD swizzle is N-MAJOR (tn = swz>>5): one XCD chunk = 2 full n-columns, so
// a B-panel's 32 m-blocks all sit on ONE XCD -> B direct-loads are L2-hits.
//
// Registers: acc 128 + aq 32 + bE/bO 64 + addr ~15 ~= 245 <= 256.

#define BM 256
#define BN 256
#define BK 64
#define NT (D_IN / BK)      // 64 K-tiles
#define LDS_A 32768         // one A buffer (256 rows x 128 B)

__device__ __forceinline__ void stage16(const f16* g, lds_char* l) {
    __builtin_amdgcn_global_load_lds(
        (const __attribute__((address_space(1))) void*)g,
        (__attribute__((address_space(3))) void*)l, 16, 0, 0);
}

#define LDS_LOAD8(p) (*(const __attribute__((address_space(3))) half8*)(p))

// 4 x ds_read_b128: rows wr*128 + q*32 + mq*16 + lr, cols (cb0|ks*64)^swz.
// abase0/abase1 fold the per-lane column XOR for ks=0/1; all else is imm.
#define LOAD_AQ(DST, PIMM, QIMM)                                            \
    do { _Pragma("unroll")                                                  \
        for (int mq = 0; mq < 2; ++mq) {                                    \
            DST[mq][0] = LDS_LOAD8(abase0 + (PIMM) + (QIMM) + mq * 2048);   \
            DST[mq][1] = LDS_LOAD8(abase1 + (PIMM) + (QIMM) + mq * 2048);   \
        } } while (0)

#define CLUST(Q, AV, BV)                                                    \
    do { _Pragma("unroll")                                                  \
        for (int mq = 0; mq < 2; ++mq)                                      \
            _Pragma("unroll")                                               \
            for (int fn = 0; fn < 4; ++fn)                                  \
                _Pragma("unroll")                                           \
                for (int ks = 0; ks < 2; ++ks)                              \
                    acc[(Q)*2+mq][fn] =                                     \
                        __builtin_amdgcn_mfma_f32_16x16x32_f16(             \
                            AV[mq][ks], BV[fn][ks],                         \
                            acc[(Q)*2+mq][fn], 0, 0, 0);                    \
    } while (0)

#define FENCE()    asm volatile("" ::: "memory")
#define BAR()      __builtin_amdgcn_s_barrier()
#define VMCNT(N)   asm volatile("s_waitcnt vmcnt(" #N ")" ::: "memory")
#define PRIO(x)    __builtin_amdgcn_s_setprio(x)

// One K-tile. PIMM = (t&1)*32768 read parity; DSTW = stage dest (parity^1);
// BC = B(t) bank (consumed); BN_ = B(t+1) bank (loaded); FULL = stages+loads.
#define TILE_BODY(TNEXT, PIMM, DSTW, BC, BN_, FULL)                         \
    do {                                                                    \
        VMCNT(8);                                      /* retire A(t) */    \
        BAR();                                                              \
        LOAD_AQ(aqa, PIMM, 0);                         /* aQ0 */            \
        if (FULL) {                                                         \
            const f16* sA = gA + (size_t)(TNEXT) * BK;                      \
            stage16(sA,                    DSTW);                           \
            stage16(sA + (size_t)64  * K,  (DSTW) + 8192);                  \
            stage16(sA + (size_t)128 * K,  (DSTW) + 16384);                 \
            stage16(sA + (size_t)192 * K,  (DSTW) + 24576);                 \
            FENCE();                                   /* A before B */     \
            _Pragma("unroll")                                               \
            for (int fn = 0; fn < 4; ++fn)                                  \
                _Pragma("unroll")                                           \
                for (int ks = 0; ks < 2; ++ks)                              \
                    BN_[fn][ks] = *reinterpret_cast<const half8*>(          \
                        gB4[fn] + (size_t)(TNEXT) * BK + ks * 32);          \
            VMCNT(12);                                 /* retire B(t) */    \
        } else {                                                            \
            VMCNT(0);                                  /* tail drain */     \
        }                                                                   \
        LOAD_AQ(aqb, PIMM, 4096);                      /* aQ1 */            \
        PRIO(1); CLUST(0, aqa, BC); PRIO(0);                                \
        LOAD_AQ(aqa, PIMM, 8192);                      /* aQ2 */            \
        PRIO(1); CLUST(1, aqb, BC); PRIO(0);                                \
        LOAD_AQ(aqb, PIMM, 12288);                     /* aQ3 */            \
        PRIO(1); CLUST(2, aqa, BC); PRIO(0);                                \
        PRIO(1); CLUST(3, aqb, BC); PRIO(0);                                \
    } while (0)

__global__ __launch_bounds__(512, 2)
void gemm_breg(const f16* __restrict__ A, const f16* __restrict__ B,
               const float* __restrict__ bias,
               const float* __restrict__ oscale_p, const int* __restrict__ ozp_p,
               float* __restrict__ C)
{
    __shared__ __align__(1024) char smem_[2 * LDS_A];   // 64 KiB, A only
    lds_char* smem = (lds_char*)smem_;
    constexpr int K = D_IN, N = D_OUT;

    // XCD-aware bijective swizzle, N-MAJOR tile order (grid 512, cpx = 64):
    // one XCD chunk = 64 swz = 2 full n-columns x 32 m -> B-panel L2-local.
    int nwg = gridDim.x;
    int cpx = nwg >> 3;
    int bid = blockIdx.x;
    int swz = (bid & 7) * cpx + (bid >> 3);
    int m0 = (swz & 31) * BM;
    int n0 = (swz >> 5) * BN;

    int tid = threadIdx.x;
    int l   = tid & 63;
    int wv  = tid >> 6;                      // 0..7
    int wr  = wv >> 2;                       // 0..1 (M)
    int wc  = wv & 3;                        // 0..3 (N)
    int lr  = l & 15;

    // A staging: lane l -> row wv*8 + (l>>3), phys slot l&7;
    // pre-swizzled global col = ((l&7) ^ (l>>3)) * 8 f16 (rule 21).
    int srow = wv * 8 + (l >> 3);
    int scol = ((l & 7) ^ (l >> 3)) * 8;
    const f16* gA = A + (size_t)(m0 + srow) * K + scol;
    lds_char* dst0 = smem + wv * 1024 + l * 16;
    lds_char* dst1 = dst0 + LDS_A;

    // A read bases: byte = (wr*128 + lr)*128 + ((cb0 + ks*64) ^ swzr)
    int cb0  = (l >> 4) * 16;
    int swzr = (l & 7) << 4;
    int c0   = cb0 ^ swzr;
    lds_char* abase0 = smem + (wr * 128 + lr) * 128 + c0;
    lds_char* abase1 = smem + (wr * 128 + lr) * 128 + (c0 ^ 64);

    // B direct-load bases: row n0 + wc*64 + fn*16 + lr, col (l>>4)*8 f16.
    const f16* gB4[4];
    #pragma unroll
    for (int fn = 0; fn < 4; ++fn)
        gB4[fn] = B + (size_t)(n0 + wc * 64 + fn * 16 + lr) * K + (l >> 4) * 8;

    f32x4 acc[8][4] = {};                    // [mf][fn]
    half8 aqa[2][2], aqb[2][2];
    half8 bE[4][2], bO[4][2];

    // ---- prologue: stage A(0) -> buf0, load B(0) -> bE, drain, barrier
    stage16(gA,                   dst0);
    stage16(gA + (size_t)64  * K, dst0 + 8192);
    stage16(gA + (size_t)128 * K, dst0 + 16384);
    stage16(gA + (size_t)192 * K, dst0 + 24576);
    FENCE();
    #pragma unroll
    for (int fn = 0; fn < 4; ++fn)
        #pragma unroll
        for (int ks = 0; ks < 2; ++ks)
            bE[fn][ks] = *reinterpret_cast<const half8*>(gB4[fn] + ks * 32);
    VMCNT(0);
    BAR();

    // ---- main loop: tiles 0..61 (31 x 2), then peel 62 (full) + 63 (tail)
    for (int t = 0; t < NT - 2; t += 2) {
        TILE_BODY(t + 1, 0,     dst1, bE, bO, true);
        TILE_BODY(t + 2, 32768, dst0, bO, bE, true);
    }
    TILE_BODY(63, 0,     dst1, bE, bO, true);    // tile 62
    TILE_BODY(64, 32768, dst0, bO, bE, false);   // tile 63 (tail)

    // ---- epilogue: bias + fake-quantize (round-half-even = jnp.round)
    float os  = oscale_p[0];
    float ozp = (float)ozp_p[0];
    float inv = 1.0f / os;
    #pragma unroll
    for (int mf = 0; mf < 8; ++mf) {
        int rowb = m0 + wr * 128 + mf * 16 + (l >> 4) * 4;
        #pragma unroll
        for (int fn = 0; fn < 4; ++fn) {
            int col = n0 + wc * 64 + fn * 16 + lr;
            float bv = bias[col];
            f32x4 v = acc[mf][fn];
            #pragma unroll
            for (int j = 0; j < 4; ++j) {
                float o = v[j] + bv;
                float q = rintf(o * inv) + ozp;
                q = fminf(fmaxf(q, 0.0f), 255.0f);
                C[(size_t)(rowb + j) * N + col] = (q - ozp) * os;
            }
        }
    }
}

// ---------------- launch ----------------

extern "C" void kernel_launch(void* const* d_in, const int* in_sizes, int n_in,
                              void* d_out, int out_size, void* d_ws, size_t ws_size,
                              hipStream_t stream) {
    const float* x      = (const float*)d_in[0];
    const int*   w8     = (const int*)d_in[1];
    const float* wscale = (const float*)d_in[2];
    const int*   wzp    = (const int*)d_in[3];
    const float* bias   = (const float*)d_in[4];
    const float* oscale = (const float*)d_in[5];
    const int*   ozp    = (const int*)d_in[6];
    float* out = (float*)d_out;

    const size_t x_elems = (size_t)TOKENS * D_IN;
    const size_t w_elems = (size_t)D_OUT * D_IN;
    const size_t need = (x_elems + w_elems) * sizeof(f16);
    if (ws_size < need) return;

    f16* xh = (f16*)d_ws;
    f16* wh = xh + x_elems;

    {
        int blocks = (int)(x_elems / 4 / 256);
        cvt_x_kernel<<<blocks, 256, 0, stream>>>(x, xh);
    }
    {
        int blocks = (int)(w_elems / 4 / 256);
        cvt_w_kernel<<<blocks, 256, 0, stream>>>(w8, wh, wscale, wzp);
    }
    {
        int grid = (TOKENS / BM) * (D_OUT / BN);   // 32 * 16 = 512, %8 == 0
        gemm_breg<<<grid, 512, 0, stream>>>(xh, wh, bias, oscale, ozp, out);
    }
}

// Round 12
// 312.978 us; speedup vs baseline: 1.6775x; 1.2900x over previous
//
#include <hip/hip_runtime.h>

#define TOKENS 8192
#define D_IN   4096
#define D_OUT  4096

typedef _Float16 f16;
typedef __attribute__((ext_vector_type(8)))  _Float16 half8;
typedef __attribute__((ext_vector_type(16))) float    f32x16;
typedef __attribute__((address_space(3))) char        lds_char;

// ---------------- conversion kernels ----------------

__global__ void cvt_x_kernel(const float* __restrict__ x, f16* __restrict__ xh) {
    size_t i = ((size_t)blockIdx.x * blockDim.x + threadIdx.x) * 4;
    float4 v = *reinterpret_cast<const float4*>(x + i);
    union { f16 h[4]; uint2 u; } p;
    p.h[0] = (f16)v.x; p.h[1] = (f16)v.y; p.h[2] = (f16)v.z; p.h[3] = (f16)v.w;
    *reinterpret_cast<uint2*>(xh + i) = p.u;
}

__global__ void cvt_w_kernel(const int* __restrict__ w, f16* __restrict__ wh,
                             const float* __restrict__ scale_p,
                             const int* __restrict__ zp_p) {
    size_t i = ((size_t)blockIdx.x * blockDim.x + threadIdx.x) * 4;
    float s = scale_p[0];
    float z = (float)zp_p[0];
    int4 v = *reinterpret_cast<const int4*>(w + i);
    union { f16 h[4]; uint2 u; } p;
    p.h[0] = (f16)(((float)v.x - z) * s);
    p.h[1] = (f16)(((float)v.y - z) * s);
    p.h[2] = (f16)(((float)v.z - z) * s);
    p.h[3] = (f16)(((float)v.w - z) * s);
    *reinterpret_cast<uint2*>(wh + i) = p.u;
}

// ---------------- GEMM: 256x256, BK=64, 8 waves, 32x32x16 MFMA ------------
// R12 = R6's proven sync skeleton (best: 269us / 46% MfmaUtil; R3-R8 showed
// sync restructures are NOT the lever; R11 showed B must stay LDS-staged for
// L2 locality) + MFMA shape swap 16x16x32 -> 32x32x16 f16:
//   pipe ceiling 1955 -> 2178 TF (+11%, m23/m64), and 8 long MFMAs per
//   cluster instead of 16 short ones (fewer issue slots, deeper pipe for
//   the scheduler to hide ds_reads under). LDS bytes, stage geometry,
//   vmcnt ledger, swizzle: all unchanged from R6.
//
// Fragment mappings (32x32x16 f16): A/B lane l: row/col = l&31,
// k = (l>>5)*8 + e (8 contiguous f16 = 16B = one b128 read).
// C/D (m74/m101, HW-verified): col = l&31,
// row = (reg&3) + 8*(reg>>2) + 4*(l>>5), reg in [0,16).
//
// LDS swizzle: phys_colbyte = logical ^ ((row&7)<<4). For 32x32 reads,
// logical colbyte = ks*32 + (l>>5)*16 -> phys(ks) = phys(0) ^ (ks<<5)
// (bitwise: ks only occupies bits 5-6). XOR can't fold into ds_read imm
// offsets -> 4 precomputed per-tile base pointers per operand; the m-tile
// index folds as +mt*4096 imm.
//
// vmcnt ledger (per wave, steady state; identical to R6): enter tile t with
// 2 outstanding [A13(t)]. ph0 +B01(t+1) ->4. ph1 +B23(t+1) ->6; VMCNT(4)
// drains A13(t), BAR, ph2 reads A-half1; +A02(t+1) ->6. ph3 +A13(t+1) ->8
// (FENCE pins issue order); VMCNT(2) drains B+A02(t+1); BAR. Last tile
// peeled with VMCNT(0)+BAR (R2 lesson). Protocol (R5 lesson): drain ->
// barrier -> ds_read at both consume points.

#define BM 256
#define BN 256
#define BK 64
#define NT (D_IN / BK)      // 64 K-tiles
#define LDS_BUF   65536
#define LDS_B_OFF 32768

__device__ __forceinline__ void stage16(const f16* g, lds_char* l) {
    __builtin_amdgcn_global_load_lds(
        (const __attribute__((address_space(1))) void*)g,
        (__attribute__((address_space(3))) void*)l, 16, 0, 0);
}

#define LDS_LOAD8(p) (*(const __attribute__((address_space(3))) half8*)(p))

// a[mh][ks] <- A-half QM rows (wr*128 + QM*64 + mh*32 + (l&31))
#define LOAD_AH(QM)                                                         \
    do { _Pragma("unroll")                                                  \
        for (int mh = 0; mh < 2; ++mh)                                      \
            _Pragma("unroll")                                               \
            for (int ks = 0; ks < 4; ++ks)                                  \
                a[mh][ks] = LDS_LOAD8(pAk[ks] + ((QM)*2 + mh) * 4096);      \
    } while (0)

// BV[ks] <- B rows (wc*64 + QN*32 + (l&31))
#define LOAD_BH(BV, QN)                                                     \
    do { _Pragma("unroll")                                                  \
        for (int ks = 0; ks < 4; ++ks)                                      \
            BV[ks] = LDS_LOAD8(pBk[ks] + (QN) * 4096);                      \
    } while (0)

// 8 MFMA: quadrant (QM, QN) = m-tiles {2QM,2QM+1} x n-tile QN x 4 k-steps
#define MFMA_Q(QM, QN, BV)                                                  \
    do { _Pragma("unroll")                                                  \
        for (int mh = 0; mh < 2; ++mh)                                      \
            _Pragma("unroll")                                               \
            for (int ks = 0; ks < 4; ++ks)                                  \
                acc[(QM)*2 + mh][QN] =                                      \
                    __builtin_amdgcn_mfma_f32_32x32x16_f16(                 \
                        a[mh][ks], BV[ks], acc[(QM)*2 + mh][QN], 0, 0, 0);  \
    } while (0)

#define FENCE()    asm volatile("" ::: "memory")
#define BAR()      __builtin_amdgcn_s_barrier()
#define VMCNT(N)   asm volatile("s_waitcnt vmcnt(" #N ")" ::: "memory")
#define PRIO(x)    __builtin_amdgcn_s_setprio(x)

__global__ __launch_bounds__(512, 2)
void gemm32(const f16* __restrict__ A, const f16* __restrict__ B,
            const float* __restrict__ bias,
            const float* __restrict__ oscale_p, const int* __restrict__ ozp_p,
            float* __restrict__ C)
{
    __shared__ __align__(1024) char smem_[2 * LDS_BUF];   // 128 KiB
    lds_char* smem = (lds_char*)smem_;
    constexpr int K = D_IN, N = D_OUT;

    // XCD-aware bijective swizzle (grid = 512, divisible by 8)
    int nwg = gridDim.x;
    int cpx = nwg >> 3;
    int bid = blockIdx.x;
    int swz = (bid & 7) * cpx + (bid >> 3);
    int ntn = N / BN;                        // 16
    int m0 = (swz / ntn) * BM;
    int n0 = (swz % ntn) * BN;

    int tid = threadIdx.x;
    int l   = tid & 63;
    int wv  = tid >> 6;                      // 0..7
    int wr  = wv >> 2;                       // 0..1 (M)
    int wc  = wv & 3;                        // 0..3 (N)

    // staging: lane l -> row = wv*8 + (l>>3), phys slot = l&7;
    // pre-swizzled global col = ((l&7) ^ (l>>3)) * 8 f16 (rule 21).
    int srow = wv * 8 + (l >> 3);
    int scol = ((l & 7) ^ (l >> 3)) * 8;
    const f16* gA = A + (size_t)(m0 + srow) * K + scol;
    const f16* gB = B + (size_t)(n0 + srow) * K + scol;
    lds_char* dstbase = smem + wv * 1024 + l * 16;

    // read-side per-lane constants (32x32 fragment addressing)
    int lrow = l & 31;
    int c00  = ((l >> 5) * 16) ^ ((l & 7) << 4);   // phys col, ks=0
    int arow = (wr * 128 + lrow) * 128;            // A row-base (byte)
    int brow = LDS_B_OFF + (wc * 64 + lrow) * 128; // B row-base (byte)

    f32x16 acc[4][2] = {};                   // [mt][nt]
    half8 a[2][4], b0v[4], b1v[4];

    // ---- prologue: stage tile 0 -> buffer 0, drain, barrier
    #pragma unroll
    for (int q = 0; q < 4; ++q) stage16(gA + (size_t)q * 64 * K, dstbase + q * 8192);
    #pragma unroll
    for (int q = 0; q < 4; ++q) stage16(gB + (size_t)q * 64 * K, dstbase + LDS_B_OFF + q * 8192);
    VMCNT(0);
    BAR();

    for (int t = 0; t < NT - 1; ++t) {
        const lds_char* buf = smem + (t & 1) * LDS_BUF;
        lds_char* dst = dstbase + ((t + 1) & 1) * LDS_BUF;
        const f16* nA = gA + (size_t)(t + 1) * BK;
        const f16* nB = gB + (size_t)(t + 1) * BK;

        // per-tile read bases: 4 per operand (ks-XOR can't be an imm)
        const lds_char* pAk[4];
        const lds_char* pBk[4];
        #pragma unroll
        for (int ks = 0; ks < 4; ++ks) {
            pAk[ks] = buf + arow + (c00 ^ (ks << 5));
            pBk[ks] = buf + brow + (c00 ^ (ks << 5));
        }

        // ---- phase 0: reads for quad (0,0); stage B01(t+1)
        LOAD_AH(0);
        LOAD_BH(b0v, 0);
        stage16(nB,                      dst + LDS_B_OFF);
        stage16(nB + (size_t)64 * K,     dst + LDS_B_OFF + 8192);
        BAR();
        PRIO(1); MFMA_Q(0, 0, b0v); PRIO(0);

        // ---- phase 1: b1 reads merge into (0,0)'s shadow; stage B23(t+1)
        LOAD_BH(b1v, 1);
        stage16(nB + (size_t)128 * K,    dst + LDS_B_OFF + 2 * 8192);
        stage16(nB + (size_t)192 * K,    dst + LDS_B_OFF + 3 * 8192);
        BAR();
        PRIO(1); MFMA_Q(0, 1, b1v); PRIO(0);

        // ---- phase 2: A13(t) consume point (drain -> barrier -> read)
        VMCNT(4);
        BAR();
        LOAD_AH(1);
        stage16(nA,                      dst);
        stage16(nA + (size_t)128 * K,    dst + 2 * 8192);
        BAR();
        PRIO(1); MFMA_Q(1, 1, b1v); PRIO(0);

        // ---- phase 3: stage A13(t+1) (fenced after A02 for ledger order)
        FENCE();
        stage16(nA + (size_t)64 * K,     dst + 8192);
        stage16(nA + (size_t)192 * K,    dst + 3 * 8192);
        BAR();
        PRIO(1); MFMA_Q(1, 0, b0v); PRIO(0);

        // ---- tile boundary: drain next tile's B + A02, barrier, proceed
        VMCNT(2);
        BAR();
    }

    // ===== peeled final tile (t = NT-1): no staging, full drain first =====
    {
        const lds_char* buf = smem + ((NT - 1) & 1) * LDS_BUF;
        const lds_char* pAk[4];
        const lds_char* pBk[4];
        #pragma unroll
        for (int ks = 0; ks < 4; ++ks) {
            pAk[ks] = buf + arow + (c00 ^ (ks << 5));
            pBk[ks] = buf + brow + (c00 ^ (ks << 5));
        }

        VMCNT(0);     // A13 of the final tile still in flight at entry
        BAR();        // collective: every wave's slices resident

        LOAD_AH(0);
        LOAD_BH(b0v, 0);
        LOAD_BH(b1v, 1);
        PRIO(1);
        MFMA_Q(0, 0, b0v);
        MFMA_Q(0, 1, b1v);
        PRIO(0);
        LOAD_AH(1);
        PRIO(1);
        MFMA_Q(1, 1, b1v);
        MFMA_Q(1, 0, b0v);
        PRIO(0);
    }

    // ---- epilogue: bias + fake-quantize (round-half-even = jnp.round)
    // C/D 32x32 layout: col = l&31, row = (r&3) + 8*(r>>2) + 4*(l>>5)
    float os  = oscale_p[0];
    float ozp = (float)ozp_p[0];
    float inv = 1.0f / os;
    #pragma unroll
    for (int mt = 0; mt < 4; ++mt) {
        int rowb = m0 + wr * 128 + mt * 32 + 4 * (l >> 5);
        #pragma unroll
        for (int nt = 0; nt < 2; ++nt) {
            int col = n0 + wc * 64 + nt * 32 + (l & 31);
            float bv = bias[col];
            f32x16 v = acc[mt][nt];
            #pragma unroll
            for (int r = 0; r < 16; ++r) {
                int row = rowb + (r & 3) + 8 * (r >> 2);
                float o = v[r] + bv;
                float q = rintf(o * inv) + ozp;
                q = fminf(fmaxf(q, 0.0f), 255.0f);
                C[(size_t)row * N + col] = (q - ozp) * os;
            }
        }
    }
}

// ---------------- launch ----------------

extern "C" void kernel_launch(void* const* d_in, const int* in_sizes, int n_in,
                              void* d_out, int out_size, void* d_ws, size_t ws_size,
                              hipStream_t stream) {
    const float* x      = (const float*)d_in[0];
    const int*   w8     = (const int*)d_in[1];
    const float* wscale = (const float*)d_in[2];
    const int*   wzp    = (const int*)d_in[3];
    const float* bias   = (const float*)d_in[4];
    const float* oscale = (const float*)d_in[5];
    const int*   ozp    = (const int*)d_in[6];
    float* out = (float*)d_out;

    const size_t x_elems = (size_t)TOKENS * D_IN;
    const size_t w_elems = (size_t)D_OUT * D_IN;
    const size_t need = (x_elems + w_elems) * sizeof(f16);
    if (ws_size < need) return;

    f16* xh = (f16*)d_ws;
    f16* wh = xh + x_elems;

    {
        int blocks = (int)(x_elems / 4 / 256);
        cvt_x_kernel<<<blocks, 256, 0, stream>>>(x, xh);
    }
    {
        int blocks = (int)(w_elems / 4 / 256);
        cvt_w_kernel<<<blocks, 256, 0, stream>>>(w8, wh, wscale, wzp);
    }
    {
        int grid = (TOKENS / BM) * (D_OUT / BN);   // 32 * 16 = 512, %8 == 0
        gemm32<<<grid, 512, 0, stream>>>(xh, wh, bias, oscale, ozp, out);
    }
}

// Round 13
// 292.365 us; speedup vs baseline: 1.7958x; 1.0705x over previous
//
#include <hip/hip_runtime.h>

#define TOKENS 8192
#define D_IN   4096
#define D_OUT  4096

typedef _Float16 f16;
typedef __attribute__((ext_vector_type(8))) _Float16 half8;
typedef __attribute__((ext_vector_type(4))) float    f32x4;
typedef __attribute__((address_space(3))) char       lds_char;

// ---------------- conversion kernels ----------------

__global__ void cvt_x_kernel(const float* __restrict__ x, f16* __restrict__ xh) {
    size_t i = ((size_t)blockIdx.x * blockDim.x + threadIdx.x) * 4;
    float4 v = *reinterpret_cast<const float4*>(x + i);
    union { f16 h[4]; uint2 u; } p;
    p.h[0] = (f16)v.x; p.h[1] = (f16)v.y; p.h[2] = (f16)v.z; p.h[3] = (f16)v.w;
    *reinterpret_cast<uint2*>(xh + i) = p.u;
}

__global__ void cvt_w_kernel(const int* __restrict__ w, f16* __restrict__ wh,
                             const float* __restrict__ scale_p,
                             const int* __restrict__ zp_p) {
    size_t i = ((size_t)blockIdx.x * blockDim.x + threadIdx.x) * 4;
    float s = scale_p[0];
    float z = (float)zp_p[0];
    int4 v = *reinterpret_cast<const int4*>(w + i);
    union { f16 h[4]; uint2 u; } p;
    p.h[0] = (f16)(((float)v.x - z) * s);
    p.h[1] = (f16)(((float)v.y - z) * s);
    p.h[2] = (f16)(((float)v.z - z) * s);
    p.h[3] = (f16)(((float)v.w - z) * s);
    *reinterpret_cast<uint2*>(wh + i) = p.u;
}

// ---------------- GEMM: 256x256, BK=32, 8 waves, 4-buffer deep pipeline ---
// R13. Synthesis of R3-R12:
//  - 16x16x32 shape (R12's 32x32 = 2.5e7 bank conflicts; 16-row-span
//    fragment reads are the empirically conflict-free pattern: R6/R9 = 0).
//  - B stays LDS-staged (R11's direct-to-reg: FETCH 295->545MB, HBM-bound).
//  - 1 block/CU, 8 waves 2Mx4N (R9's 2-block experiment: LDS-port-bound).
//  - NEW LEVER: stage->drain lead. R6's tightest edge was ONE phase
//    (~640cy < 900cy HBM latency) -> stall at every tile boundary, plus
//    6 barriers/tile of lockstep. Here: BK=32, 4 LDS buffers x 32KB,
//    staged THREE tiles ahead (lead ~3x1400cy), ONE vmcnt + ONE barrier
//    per K-tile. Reads stay same-epoch as their MFMAs (compiler emits
//    fine-grained lgkm waits -- R4 proved manual lgkm0 unnecessary);
//    no extra register banks (R10's deep-lead failure mode).
//
// vmcnt ledger (4 stages/tile, FIFO): enter tile t with 8 outstanding
// (tiles t+1, t+2). Issue 4 for t+3 -> 12. Boundary VMCNT(8) retires
// exactly tile t+1's four (3-tile-old, ~4200cy lead). Tail peeled:
// t=NT-3 no stage, VMCNT(4); t=NT-2 VMCNT(0); t=NT-1 no wait (R2 lesson:
// counted drains no-op when the queue is short).
// Protocol (R5 lesson): drain -> barrier -> read; the single boundary
// VMCNT+BAR is the only consume point (tile t+1's buffer).
// WAR: stages at tile t target buf[(t+3)&3], last read at tile t-1 --
// reads pinned inside their tile by the boundary VMCNT "memory" asm,
// and two barriers separate them from the overwriting DMA.
//
// LDS geometry (R9's refcheck'd 64B-row pair): rows = 64B (BK=32 f16),
// 4 slots x 16B, swizzle phys_slot = slot ^ ((row>>1)&3).
//   write (global_load_lds linear, rule 21): lane l -> row wv*16+(l>>2),
//   phys slot l&3, pre-swizzled global col ((l&3)^((srow>>1)&3))*8 f16.
//   read: colsel = ((l>>4) ^ ((lr>>1)&3))<<4; row-base*64 + fm*1024 imm.
// Buffer: A rows 0..255 at [0,16K), B at [16K,32K). 4 buffers = 128KB.

#define BM 256
#define BN 256
#define BK 32
#define NT (D_IN / BK)      // 128 K-tiles
#define BUFSZ 32768
#define B_OFF 16384

__device__ __forceinline__ void stage16(const f16* g, lds_char* l) {
    __builtin_amdgcn_global_load_lds(
        (const __attribute__((address_space(1))) void*)g,
        (__attribute__((address_space(3))) void*)l, 16, 0, 0);
}

#define LDS_LOAD8(p) (*(const __attribute__((address_space(3))) half8*)(p))

#define BAR()      __builtin_amdgcn_s_barrier()
#define VMCNT(N)   asm volatile("s_waitcnt vmcnt(" #N ")" ::: "memory")
#define PRIO(x)    __builtin_amdgcn_s_setprio(x)

#define READS_AND_MFMA(BUF)                                                 \
    do {                                                                    \
        _Pragma("unroll")                                                   \
        for (int fm = 0; fm < 8; ++fm)                                      \
            a[fm] = LDS_LOAD8((BUF) + aoff + fm * 1024);                    \
        _Pragma("unroll")                                                   \
        for (int fn = 0; fn < 4; ++fn)                                      \
            b[fn] = LDS_LOAD8((BUF) + boff + fn * 1024);                    \
        PRIO(1);                                                            \
        _Pragma("unroll")                                                   \
        for (int fm = 0; fm < 8; ++fm)                                      \
            _Pragma("unroll")                                               \
            for (int fn = 0; fn < 4; ++fn)                                  \
                acc[fm][fn] = __builtin_amdgcn_mfma_f32_16x16x32_f16(       \
                    a[fm], b[fn], acc[fm][fn], 0, 0, 0);                    \
        PRIO(0);                                                            \
    } while (0)

#define STAGE_TILE(TT)                                                      \
    do {                                                                    \
        lds_char* dst = dstbase + ((TT) & 3) * BUFSZ;                       \
        const f16* sA = gA + (size_t)(TT) * BK;                             \
        const f16* sB = gB + (size_t)(TT) * BK;                             \
        stage16(sA,                    dst);                                \
        stage16(sA + (size_t)128 * K,  dst + 8192);                         \
        stage16(sB,                    dst + B_OFF);                        \
        stage16(sB + (size_t)128 * K,  dst + B_OFF + 8192);                 \
    } while (0)

__global__ __launch_bounds__(512, 2)
void gemm_dp(const f16* __restrict__ A, const f16* __restrict__ B,
             const float* __restrict__ bias,
             const float* __restrict__ oscale_p, const int* __restrict__ ozp_p,
             float* __restrict__ C)
{
    __shared__ __align__(1024) char smem_[4 * BUFSZ];   // 128 KiB
    lds_char* smem = (lds_char*)smem_;
    constexpr int K = D_IN, N = D_OUT;

    // XCD-aware bijective swizzle (grid = 512, divisible by 8)
    int nwg = gridDim.x;
    int cpx = nwg >> 3;
    int bid = blockIdx.x;
    int swz = (bid & 7) * cpx + (bid >> 3);
    int ntn = N / BN;                        // 16
    int m0 = (swz / ntn) * BM;
    int n0 = (swz % ntn) * BN;

    int tid = threadIdx.x;
    int l   = tid & 63;
    int wv  = tid >> 6;                      // 0..7
    int wr  = wv >> 2;                       // 0..1 (M)
    int wc  = wv & 3;                        // 0..3 (N)
    int lr  = l & 15;

    // staging: one block-wide stage16 = 8KB = 128 rows x 64B.
    // lane l -> row wv*16 + (l>>2), phys slot l&3;
    // pre-swizzled global col = ((l&3) ^ ((srow>>1)&3)) * 8 f16 (rule 21).
    int srow = wv * 16 + (l >> 2);
    int scol = ((l & 3) ^ ((srow >> 1) & 3)) * 8;
    const f16* gA = A + (size_t)(m0 + srow) * K + scol;
    const f16* gB = B + (size_t)(n0 + srow) * K + scol;
    lds_char* dstbase = smem + wv * 1024 + l * 16;

    // read offsets (loop-invariant; fm/fn are imm offsets):
    // row = base*16 + lr -> (row>>1)&3 == (lr>>1)&3 (16-multiples drop out)
    int colsel = ((l >> 4) ^ ((lr >> 1) & 3)) << 4;
    int aoff = (wr * 128 + lr) * 64 + colsel;
    int boff = B_OFF + (wc * 64 + lr) * 64 + colsel;

    f32x4 acc[8][4] = {};
    half8 a[8], b[4];

    // ---- prologue: stage tiles 0,1,2; retire tile 0; barrier
    STAGE_TILE(0);
    STAGE_TILE(1);
    STAGE_TILE(2);
    VMCNT(8);       // tile 0 resident (tiles 1,2 in flight)
    BAR();

    // ---- main loop: one vmcnt + one barrier per K-tile
    for (int t = 0; t < NT - 3; ++t) {
        const lds_char* buf = smem + (t & 3) * BUFSZ;
        STAGE_TILE(t + 3);
        READS_AND_MFMA(buf);
        VMCNT(8);   // retire tile t+1's 4 stages (3-tile lead)
        BAR();
    }
    // ---- peeled tail: t = NT-3, NT-2, NT-1 (no stages, decaying drains)
    {
        READS_AND_MFMA(smem + ((NT - 3) & 3) * BUFSZ);
        VMCNT(4);   // tile NT-2 resident
        BAR();
        READS_AND_MFMA(smem + ((NT - 2) & 3) * BUFSZ);
        VMCNT(0);   // tile NT-1 resident
        BAR();
        READS_AND_MFMA(smem + ((NT - 1) & 3) * BUFSZ);
    }

    // ---- epilogue: bias + fake-quantize (round-half-even = jnp.round)
    float os  = oscale_p[0];
    float ozp = (float)ozp_p[0];
    float inv = 1.0f / os;
    #pragma unroll
    for (int fm = 0; fm < 8; ++fm) {
        int rowb = m0 + wr * 128 + fm * 16 + (l >> 4) * 4;
        #pragma unroll
        for (int fn = 0; fn < 4; ++fn) {
            int col = n0 + wc * 64 + fn * 16 + lr;
            float bv = bias[col];
            f32x4 v = acc[fm][fn];
            #pragma unroll
            for (int j = 0; j < 4; ++j) {
                float o = v[j] + bv;
                float q = rintf(o * inv) + ozp;
                q = fminf(fmaxf(q, 0.0f), 255.0f);
                C[(size_t)(rowb + j) * N + col] = (q - ozp) * os;
            }
        }
    }
}

// ---------------- launch ----------------

extern "C" void kernel_launch(void* const* d_in, const int* in_sizes, int n_in,
                              void* d_out, int out_size, void* d_ws, size_t ws_size,
                              hipStream_t stream) {
    const float* x      = (const float*)d_in[0];
    const int*   w8     = (const int*)d_in[1];
    const float* wscale = (const float*)d_in[2];
    const int*   wzp    = (const int*)d_in[3];
    const float* bias   = (const float*)d_in[4];
    const float* oscale = (const float*)d_in[5];
    const int*   ozp    = (const int*)d_in[6];
    float* out = (float*)d_out;

    const size_t x_elems = (size_t)TOKENS * D_IN;
    const size_t w_elems = (size_t)D_OUT * D_IN;
    const size_t need = (x_elems + w_elems) * sizeof(f16);
    if (ws_size < need) return;

    f16* xh = (f16*)d_ws;
    f16* wh = xh + x_elems;

    {
        int blocks = (int)(x_elems / 4 / 256);
        cvt_x_kernel<<<blocks, 256, 0, stream>>>(x, xh);
    }
    {
        int blocks = (int)(w_elems / 4 / 256);
        cvt_w_kernel<<<blocks, 256, 0, stream>>>(w8, wh, wscale, wzp);
    }
    {
        int grid = (TOKENS / BM) * (D_OUT / BN);   // 32 * 16 = 512, %8 == 0
        gemm_dp<<<grid, 512, 0, stream>>>(xh, wh, bias, oscale, ozp, out);
    }
}

// Round 14
// 292.123 us; speedup vs baseline: 1.7973x; 1.0008x over previous
//
#include <hip/hip_runtime.h>

#define TOKENS 8192
#define D_IN   4096
#define D_OUT  4096

typedef _Float16 f16;
typedef __attribute__((ext_vector_type(8))) _Float16 half8;
typedef __attribute__((ext_vector_type(4))) float    f32x4;
typedef __attribute__((address_space(3))) char       lds_char;

// ---------------- conversion kernels ----------------

__global__ void cvt_x_kernel(const float* __restrict__ x, f16* __restrict__ xh) {
    size_t i = ((size_t)blockIdx.x * blockDim.x + threadIdx.x) * 4;
    float4 v = *reinterpret_cast<const float4*>(x + i);
    union { f16 h[4]; uint2 u; } p;
    p.h[0] = (f16)v.x; p.h[1] = (f16)v.y; p.h[2] = (f16)v.z; p.h[3] = (f16)v.w;
    *reinterpret_cast<uint2*>(xh + i) = p.u;
}

__global__ void cvt_w_kernel(const int* __restrict__ w, f16* __restrict__ wh,
                             const float* __restrict__ scale_p,
                             const int* __restrict__ zp_p) {
    size_t i = ((size_t)blockIdx.x * blockDim.x + threadIdx.x) * 4;
    float s = scale_p[0];
    float z = (float)zp_p[0];
    int4 v = *reinterpret_cast<const int4*>(w + i);
    union { f16 h[4]; uint2 u; } p;
    p.h[0] = (f16)(((float)v.x - z) * s);
    p.h[1] = (f16)(((float)v.y - z) * s);
    p.h[2] = (f16)(((float)v.z - z) * s);
    p.h[3] = (f16)(((float)v.w - z) * s);
    *reinterpret_cast<uint2*>(wh + i) = p.u;
}

// ---------------- GEMM: 256x256, BK=32, 8 waves, cross-epoch reg banks ----
// R14. R13 post-mortem: 1-bar/tile deep pipeline STILL 46% MfmaUtil =>
// sync/lead was never the lever. Model fitting R3-R13: within each epoch,
// every wave's MFMAs lgkm-wait on that SAME epoch's 12 ds_reads; barriers
// phase-align all 8 waves => the CU alternates {LDS burst 1024cy, MFMA
// burst 1241cy} per K-32 tile = 2265+bar ~ 2625 measured.
// FIX: epoch t = { stage t+3 | read tile t+1 -> bank NXT | MFMA tile t
// from bank CUR } -- MFMAs have NO dependence on this epoch's reads, so
// the LDS port runs concurrently with the MFMA pipe. Banks compile-time
// (rule 20) via x2 unroll. Geometry/swizzle/epilogue = R13 (conflict-free).
//
// vmcnt ledger (4 stages/tile, FIFO): prologue stages 0,1; VMCNT(4)
// retires 0; BAR. Pre-epoch: read 0->E; stage 2; VMCNT(4) retires 1; BAR.
// Epoch t: stage t+3; read t+1; MFMA t; VMCNT(4) retires t+2; BAR.
//   (outstanding at drain: {t+2, t+3} = 8 -> 4. Protocol (R5): the drain
//   of tile t+2 precedes the barrier that precedes its reads in t+1.)
// Tail: epoch 124 stages 127, VMCNT(4); 125: no stage, VMCNT(0); 126:
// read 127 + MFMA 126, no drain/bar needed (no further DMA); 127: MFMA.
// WAR: epoch t stages buf[(t+3)&3] = buf[(t-1)&3], read in epoch t-2;
// two barriers upstream. Reads pinned by the VMCNT "memory" clobbers.

#define BM 256
#define BN 256
#define BK 32
#define NT (D_IN / BK)      // 128 K-tiles
#define BUFSZ 32768
#define B_OFF 16384

__device__ __forceinline__ void stage16(const f16* g, lds_char* l) {
    __builtin_amdgcn_global_load_lds(
        (const __attribute__((address_space(1))) void*)g,
        (__attribute__((address_space(3))) void*)l, 16, 0, 0);
}

#define LDS_LOAD8(p) (*(const __attribute__((address_space(3))) half8*)(p))

#define BAR()      __builtin_amdgcn_s_barrier()
#define VMCNT(N)   asm volatile("s_waitcnt vmcnt(" #N ")" ::: "memory")
#define PRIO(x)    __builtin_amdgcn_s_setprio(x)

#define STAGE_TILE(TT)                                                      \
    do {                                                                    \
        lds_char* dst = dstbase + ((TT) & 3) * BUFSZ;                       \
        const f16* sA = gA + (size_t)(TT) * BK;                             \
        const f16* sB = gB + (size_t)(TT) * BK;                             \
        stage16(sA,                    dst);                                \
        stage16(sA + (size_t)128 * K,  dst + 8192);                         \
        stage16(sB,                    dst + B_OFF);                        \
        stage16(sB + (size_t)128 * K,  dst + B_OFF + 8192);                 \
    } while (0)

#define READ_BANK(AB, BB, TREAD)                                            \
    do {                                                                    \
        const lds_char* rbuf = smem + ((TREAD) & 3) * BUFSZ;                \
        _Pragma("unroll")                                                   \
        for (int fm = 0; fm < 8; ++fm)                                      \
            AB[fm] = LDS_LOAD8(rbuf + aoff + fm * 1024);                    \
        _Pragma("unroll")                                                   \
        for (int fn = 0; fn < 4; ++fn)                                      \
            BB[fn] = LDS_LOAD8(rbuf + boff + fn * 1024);                    \
    } while (0)

#define MFMA_BANK(AB, BB)                                                   \
    do {                                                                    \
        PRIO(1);                                                            \
        _Pragma("unroll")                                                   \
        for (int fm = 0; fm < 8; ++fm)                                      \
            _Pragma("unroll")                                               \
            for (int fn = 0; fn < 4; ++fn)                                  \
                acc[fm][fn] = __builtin_amdgcn_mfma_f32_16x16x32_f16(       \
                    a##AB[fm], b##BB[fn], acc[fm][fn], 0, 0, 0);            \
        PRIO(0);                                                            \
    } while (0)

__global__ __launch_bounds__(512, 2)
void gemm_xb(const f16* __restrict__ A, const f16* __restrict__ B,
             const float* __restrict__ bias,
             const float* __restrict__ oscale_p, const int* __restrict__ ozp_p,
             float* __restrict__ C)
{
    __shared__ __align__(1024) char smem_[4 * BUFSZ];   // 128 KiB
    lds_char* smem = (lds_char*)smem_;
    constexpr int K = D_IN, N = D_OUT;

    // XCD-aware bijective swizzle (grid = 512, divisible by 8)
    int nwg = gridDim.x;
    int cpx = nwg >> 3;
    int bid = blockIdx.x;
    int swz = (bid & 7) * cpx + (bid >> 3);
    int ntn = N / BN;                        // 16
    int m0 = (swz / ntn) * BM;
    int n0 = (swz % ntn) * BN;

    int tid = threadIdx.x;
    int l   = tid & 63;
    int wv  = tid >> 6;                      // 0..7
    int wr  = wv >> 2;                       // 0..1 (M)
    int wc  = wv & 3;                        // 0..3 (N)
    int lr  = l & 15;

    // staging (R13, refcheck'd): lane l -> row wv*16 + (l>>2), phys slot
    // l&3; pre-swizzled global col = ((l&3) ^ ((srow>>1)&3)) * 8 f16.
    int srow = wv * 16 + (l >> 2);
    int scol = ((l & 3) ^ ((srow >> 1) & 3)) * 8;
    const f16* gA = A + (size_t)(m0 + srow) * K + scol;
    const f16* gB = B + (size_t)(n0 + srow) * K + scol;
    lds_char* dstbase = smem + wv * 1024 + l * 16;

    // read offsets (loop-invariant; fm/fn are imm offsets)
    int colsel = ((l >> 4) ^ ((lr >> 1) & 3)) << 4;
    int aoff = (wr * 128 + lr) * 64 + colsel;
    int boff = B_OFF + (wc * 64 + lr) * 64 + colsel;

    f32x4 acc[8][4] = {};
    half8 aE[8], bE[4], aO[8], bO[4];       // even/odd epoch banks (rule 20)

    // ---- prologue: stage 0,1; retire 0; BAR
    STAGE_TILE(0);
    STAGE_TILE(1);
    VMCNT(4);
    BAR();
    // ---- pre-epoch: read tile 0 -> bank E; stage 2; retire 1; BAR
    READ_BANK(aE, bE, 0);
    STAGE_TILE(2);
    VMCNT(4);
    BAR();

    // ---- main loop, x2 unrolled (banks compile-time): epochs 0..123
    for (int t = 0; t < NT - 4; t += 2) {
        // epoch t (even): MFMA bank E (tile t), read t+1 -> O, stage t+3
        STAGE_TILE(t + 3);
        READ_BANK(aO, bO, t + 1);
        MFMA_BANK(E, E);
        VMCNT(4);       // retire tile t+2 (read next epoch)
        BAR();
        // epoch t+1 (odd): MFMA bank O (tile t+1), read t+2 -> E, stage t+4
        STAGE_TILE(t + 4);
        READ_BANK(aE, bE, t + 2);
        MFMA_BANK(O, O);
        VMCNT(4);       // retire tile t+3
        BAR();
    }
    // ---- peeled epochs 124..127 (NT = 128)
    {
        // epoch 124 (even): MFMA E(124), read 125 -> O, stage 127
        STAGE_TILE(NT - 1);
        READ_BANK(aO, bO, NT - 3);
        MFMA_BANK(E, E);
        VMCNT(4);       // retire tile 126
        BAR();
        // epoch 125: MFMA O(125), read 126 -> E, no stage
        READ_BANK(aE, bE, NT - 2);
        MFMA_BANK(O, O);
        VMCNT(0);       // retire tile 127 (R2 lesson: full drain at tail)
        BAR();
        // epoch 126: MFMA E(126), read 127 -> O; no more DMA -> no drain/bar
        READ_BANK(aO, bO, NT - 1);
        MFMA_BANK(E, E);
        // epoch 127: MFMA O(127)
        MFMA_BANK(O, O);
    }

    // ---- epilogue: bias + fake-quantize (round-half-even = jnp.round)
    float os  = oscale_p[0];
    float ozp = (float)ozp_p[0];
    float inv = 1.0f / os;
    #pragma unroll
    for (int fm = 0; fm < 8; ++fm) {
        int rowb = m0 + wr * 128 + fm * 16 + (l >> 4) * 4;
        #pragma unroll
        for (int fn = 0; fn < 4; ++fn) {
            int col = n0 + wc * 64 + fn * 16 + lr;
            float bv = bias[col];
            f32x4 v = acc[fm][fn];
            #pragma unroll
            for (int j = 0; j < 4; ++j) {
                float o = v[j] + bv;
                float q = rintf(o * inv) + ozp;
                q = fminf(fmaxf(q, 0.0f), 255.0f);
                C[(size_t)(rowb + j) * N + col] = (q - ozp) * os;
            }
        }
    }
}

// ---------------- launch ----------------

extern "C" void kernel_launch(void* const* d_in, const int* in_sizes, int n_in,
                              void* d_out, int out_size, void* d_ws, size_t ws_size,
                              hipStream_t stream) {
    const float* x      = (const float*)d_in[0];
    const int*   w8     = (const int*)d_in[1];
    const float* wscale = (const float*)d_in[2];
    const int*   wzp    = (const int*)d_in[3];
    const float* bias   = (const float*)d_in[4];
    const float* oscale = (const float*)d_in[5];
    const int*   ozp    = (const int*)d_in[6];
    float* out = (float*)d_out;

    const size_t x_elems = (size_t)TOKENS * D_IN;
    const size_t w_elems = (size_t)D_OUT * D_IN;
    const size_t need = (x_elems + w_elems) * sizeof(f16);
    if (ws_size < need) return;

    f16* xh = (f16*)d_ws;
    f16* wh = xh + x_elems;

    {
        int blocks = (int)(x_elems / 4 / 256);
        cvt_x_kernel<<<blocks, 256, 0, stream>>>(x, xh);
    }
    {
        int blocks = (int)(w_elems / 4 / 256);
        cvt_w_kernel<<<blocks, 256, 0, stream>>>(w8, wh, wscale, wzp);
    }
    {
        int grid = (TOKENS / BM) * (D_OUT / BN);   // 32 * 16 = 512, %8 == 0
        gemm_xb<<<grid, 512, 0, stream>>>(xh, wh, bias, oscale, ozp, out);
    }
}